// Round 8
// baseline (1403.306 us; speedup 1.0000x reference)
//
#include <hip/hip_runtime.h>

#define CDIM   512
#define NTOK   4096
#define TOT    (CDIM*NTOK)
#define MLPD   4096
#define EPS    1e-5f
#define QSCALE 0.1803368801111204f   // 0.125 * log2(e): softmax scale + exp2 conversion, folded into wq

typedef _Float16 f16;
typedef _Float16 f16x8 __attribute__((ext_vector_type(8)));
typedef float    f32x4 __attribute__((ext_vector_type(4)));

typedef __attribute__((address_space(3))) void lds_void;
typedef const __attribute__((address_space(1))) void glb_void;

__device__ __forceinline__ void gload16(const void* g, void* l) {
  __builtin_amdgcn_global_load_lds((glb_void*)g, (lds_void*)l, 16, 0, 0);
}

__device__ __forceinline__ f32x4 zero4() { f32x4 z; z[0]=0.f; z[1]=0.f; z[2]=0.f; z[3]=0.f; return z; }

// =====================================================================
// weight staging kernels (fp32 -> f16, permutations baked in)
// =====================================================================
// qkv: dst [4][1536][512]; row n: sect=n>>9 (q/k/v), within-sect head-major
// (n' = h*64+hd <- src channel c = hd*8+h). q rows scaled by QSCALE.
__global__ __launch_bounds__(256) void cvt_qkv(const float* __restrict__ wq,
                                               const float* __restrict__ wk,
                                               const float* __restrict__ wv,
                                               f16* __restrict__ dst) {
  int i = blockIdx.x * 256 + threadIdx.x;       // 8-elem unit, total 393216
  int k0 = (i & 63) * 8;
  int rowglob = i >> 6;
  int l = rowglob / 1536;
  int n = rowglob - l * 1536;
  int sect = n >> 9, nn = n & 511;
  int h = nn >> 6, hd = nn & 63;
  int c = hd * 8 + h;
  const float* base = (sect == 0) ? wq : (sect == 1) ? wk : wv;
  const float* src = base + (size_t)l * 262144 + c * 512 + k0;
  float scl = (sect == 0) ? QSCALE : 1.f;
  float4 a = *(const float4*)src;
  float4 b = *(const float4*)(src + 4);
  f16x8 o;
  o[0]=(f16)(a.x*scl); o[1]=(f16)(a.y*scl); o[2]=(f16)(a.z*scl); o[3]=(f16)(a.w*scl);
  o[4]=(f16)(b.x*scl); o[5]=(f16)(b.y*scl); o[6]=(f16)(b.z*scl); o[7]=(f16)(b.w*scl);
  *(f16x8*)&dst[(size_t)l * 786432 + (size_t)n * 512 + k0] = o;
}

// wp: dst [4][512][512], K-dim (cols) permuted head-major: dst[l][n][d] = wp[l][n][(d&63)*8 + (d>>6)]
__global__ __launch_bounds__(256) void cvt_wp(const float* __restrict__ wp,
                                              f16* __restrict__ dst) {
  int i = blockIdx.x * 256 + threadIdx.x;       // 8-elem unit, total 131072
  int d0 = (i & 63) * 8;
  int rowglob = i >> 6;
  int l = rowglob >> 9, n = rowglob & 511;
  int h = d0 >> 6;
  const float* src = wp + (size_t)l * 262144 + (size_t)n * 512;
  f16x8 o;
#pragma unroll
  for (int u = 0; u < 8; ++u) {
    int hd = (d0 + u) & 63;
    o[u] = (f16)src[hd * 8 + h];
  }
  *(f16x8*)&dst[(size_t)l * 262144 + (size_t)n * 512 + d0] = o;
}

// w1 / w2 straight convert (blockIdx.y selects)
__global__ __launch_bounds__(256) void cvt_12(const float* __restrict__ w1,
                                              const float* __restrict__ w2,
                                              f16* __restrict__ d1,
                                              f16* __restrict__ d2) {
  int i = blockIdx.x * 256 + threadIdx.x;       // 8-elem unit, total 1048576 per weight
  const float* src = blockIdx.y ? w2 : w1;
  f16* dst = blockIdx.y ? d2 : d1;
  size_t e = (size_t)i * 8;
  float4 a = *(const float4*)(src + e);
  float4 b = *(const float4*)(src + e + 4);
  f16x8 o;
  o[0]=(f16)a.x; o[1]=(f16)a.y; o[2]=(f16)a.z; o[3]=(f16)a.w;
  o[4]=(f16)b.x; o[5]=(f16)b.y; o[6]=(f16)b.z; o[7]=(f16)b.w;
  *(f16x8*)&dst[e] = o;
}

// =====================================================================
// fp32 tiled transpose (+ optional GN stats accumulation of the data)
// =====================================================================
template <bool STATS>
__global__ __launch_bounds__(256) void transpose_k(const float* __restrict__ src,
                                                   float* __restrict__ dst,
                                                   int R, int C,
                                                   float* __restrict__ stats) {
  __shared__ float t[64][65];
  int c0 = blockIdx.x * 64, r0 = blockIdx.y * 64;
  float s = 0.f, q = 0.f;
  for (int id = threadIdx.x; id < 1024; id += 256) {
    int row = id >> 4, cc = id & 15;
    float4 v = *(const float4*)&src[(size_t)(r0 + row) * C + c0 + cc * 4];
    *(float4*)&t[row][cc * 4] = v;
    if (STATS) {
      s += (v.x + v.y) + (v.z + v.w);
      q += (v.x*v.x + v.y*v.y) + (v.z*v.z + v.w*v.w);
    }
  }
  __syncthreads();
  for (int id = threadIdx.x; id < 1024; id += 256) {
    int row = id >> 4, cc = id & 15;
    float4 o;
    o.x = t[cc*4+0][row]; o.y = t[cc*4+1][row];
    o.z = t[cc*4+2][row]; o.w = t[cc*4+3][row];
    *(float4*)&dst[(size_t)(c0 + row) * R + r0 + cc * 4] = o;
  }
  if (STATS) {
#pragma unroll
    for (int off = 32; off > 0; off >>= 1) {
      s += __shfl_down(s, off);
      q += __shfl_down(q, off);
    }
    if ((threadIdx.x & 63) == 0) {
      atomicAdd(&stats[0], s);
      atomicAdd(&stats[1], q);
    }
  }
}

// =====================================================================
// GN apply: raw stats -> mu/rsigma inline; fp32 token-major -> f16
// =====================================================================
__global__ __launch_bounds__(256) void gn_apply2(const float* __restrict__ x,
                                                 const float* __restrict__ stats,
                                                 const float* __restrict__ g,
                                                 const float* __restrict__ b,
                                                 f16* __restrict__ out) {
  int i = blockIdx.x * 256 + threadIdx.x;       // 8-elem unit
  float mu = stats[0] * (1.f / TOT);
  float var = stats[1] * (1.f / TOT) - mu * mu;
  float rs = rsqrtf(var + EPS);
  int c0 = (i & 63) * 8;
  const float4* x4 = (const float4*)x;
  float4 a = x4[i * 2], c = x4[i * 2 + 1];
  float4 G0 = *(const float4*)(g + c0);
  float4 G1 = *(const float4*)(g + c0 + 4);
  float4 B0 = *(const float4*)(b + c0);
  float4 B1 = *(const float4*)(b + c0 + 4);
  f16x8 o;
  o[0]=(f16)((a.x-mu)*rs*G0.x+B0.x); o[1]=(f16)((a.y-mu)*rs*G0.y+B0.y);
  o[2]=(f16)((a.z-mu)*rs*G0.z+B0.z); o[3]=(f16)((a.w-mu)*rs*G0.w+B0.w);
  o[4]=(f16)((c.x-mu)*rs*G1.x+B1.x); o[5]=(f16)((c.y-mu)*rs*G1.y+B1.y);
  o[6]=(f16)((c.z-mu)*rs*G1.z+B1.z); o[7]=(f16)((c.w-mu)*rs*G1.w+B1.w);
  *(f16x8*)&out[(size_t)i * 8] = o;
}

// =====================================================================
// MFMA f16 GEMM, m97-style: global_load_lds(16B) staging, linear LDS,
// XOR-swizzle via pre-swizzled global source. C[m][n] = sum_k A[m][k]*Bw[n][k].
// MODE 0: f16 store (LDS-bounced); 1: +bias+relu f16 store; 2: fp32 C += acc+bias, +GN stats
// =====================================================================
template <int BM, int BN, int MODE>
__global__ __launch_bounds__(256) void hgemm2(const f16* __restrict__ A,
                                              const f16* __restrict__ Bw,
                                              const float* __restrict__ bias,
                                              f16* __restrict__ Cf16,
                                              float* __restrict__ Cf32,
                                              float* __restrict__ stats,
                                              int N, int K) {
  constexpr int MB = BM / 32, NB = BN / 32;     // 16x16 fragments per wave (2x2 wave grid)
  __shared__ __align__(16) f16 SM[(BM + BN) * 64];
  f16* As = SM;
  f16* Bs = SM + BM * 64;

  const int tid = threadIdx.x;
  const int lane = tid & 63, wid = tid >> 6;
  const int wm = wid >> 1, wn = wid & 1;
  const int m0 = blockIdx.y * BM, n0 = blockIdx.x * BN;
  const int l15 = lane & 15, hi = lane >> 4;

  f32x4 acc[MB][NB];
#pragma unroll
  for (int mb = 0; mb < MB; ++mb)
#pragma unroll
    for (int nb = 0; nb < NB; ++nb) acc[mb][nb] = zero4();

  for (int k0 = 0; k0 < K; k0 += 64) {
#pragma unroll
    for (int j = 0; j < BM / 32; ++j) {
      int flat = j * 256 + tid;
      int row = flat >> 3, c = flat & 7;
      gload16(&A[(size_t)(m0 + row) * K + k0 + ((c ^ (row & 7)) * 8)],
              &As[(j * 256 + wid * 64) * 8]);
    }
#pragma unroll
    for (int j = 0; j < BN / 32; ++j) {
      int flat = j * 256 + tid;
      int row = flat >> 3, c = flat & 7;
      gload16(&Bw[(size_t)(n0 + row) * K + k0 + ((c ^ (row & 7)) * 8)],
              &Bs[(j * 256 + wid * 64) * 8]);
    }
    asm volatile("s_waitcnt vmcnt(0)" ::: "memory");
    __syncthreads();
#pragma unroll
    for (int ks = 0; ks < 2; ++ks) {
      f16x8 af[MB], bf[NB];
#pragma unroll
      for (int mb = 0; mb < MB; ++mb) {
        int row = wm * (BM / 2) + mb * 16 + l15;
        af[mb] = *(const f16x8*)&As[row * 64 + ((ks * 32 + hi * 8) ^ ((row & 7) * 8))];
      }
#pragma unroll
      for (int nb = 0; nb < NB; ++nb) {
        int row = wn * (BN / 2) + nb * 16 + l15;
        bf[nb] = *(const f16x8*)&Bs[row * 64 + ((ks * 32 + hi * 8) ^ ((row & 7) * 8))];
      }
#pragma unroll
      for (int mb = 0; mb < MB; ++mb)
#pragma unroll
        for (int nb = 0; nb < NB; ++nb)
          acc[mb][nb] = __builtin_amdgcn_mfma_f32_16x16x32_f16(af[mb], bf[nb], acc[mb][nb], 0, 0, 0);
    }
    __syncthreads();
  }

  if constexpr (MODE <= 1) {
    // LDS-bounced f16 epilogue (swizzled tile, vectorized global store)
    f16* Co = SM;                               // BM*BN f16 == (BM+BN)*64 exactly
#pragma unroll
    for (int mb = 0; mb < MB; ++mb)
#pragma unroll
      for (int nb = 0; nb < NB; ++nb) {
        int colb = wn * (BN / 2) + nb * 16 + l15;
        float bv = 0.f;
        if constexpr (MODE == 1) bv = bias[n0 + colb];
#pragma unroll
        for (int r = 0; r < 4; ++r) {
          int row = wm * (BM / 2) + mb * 16 + hi * 4 + r;
          float v = acc[mb][nb][r];
          if constexpr (MODE == 1) v = fmaxf(v + bv, 0.f);
          Co[row * BN + (colb ^ ((row & 7) * 8))] = (f16)v;
        }
      }
    __syncthreads();
#pragma unroll
    for (int j = 0; j < BM * BN / 2048; ++j) {
      int flat = j * 256 + tid;
      int row = flat / (BN / 8), c = flat % (BN / 8);
      f16x8 v = *(const f16x8*)&Co[row * BN + ((c * 8) ^ ((row & 7) * 8))];
      *(f16x8*)&Cf16[(size_t)(m0 + row) * N + n0 + c * 8] = v;
    }
  } else {
    // MODE 2: fp32 accumulate (+bias) into Cf32, fused GN stats (BM=BN=64)
    float* Co = (float*)SM;                     // 64*64 f32 = 16KB
#pragma unroll
    for (int mb = 0; mb < MB; ++mb)
#pragma unroll
      for (int nb = 0; nb < NB; ++nb) {
        int colb = wn * 32 + nb * 16 + l15;
#pragma unroll
        for (int r = 0; r < 4; ++r) {
          int row = wm * 32 + mb * 16 + hi * 4 + r;
          Co[row * 64 + (colb ^ ((row & 7) * 4))] = acc[mb][nb][r];
        }
      }
    __syncthreads();
    float s_acc = 0.f, q_acc = 0.f;
#pragma unroll
    for (int j = 0; j < 4; ++j) {
      int flat = j * 256 + tid;
      int row = flat >> 4, c = flat & 15;
      float4 v = *(const float4*)&Co[row * 64 + ((c * 4) ^ ((row & 7) * 4))];
      float4 b4 = *(const float4*)&bias[n0 + c * 4];
      float* gp = &Cf32[(size_t)(m0 + row) * N + n0 + c * 4];
      float4 old = *(const float4*)gp;
      float4 rr;
      rr.x = old.x + v.x + b4.x; rr.y = old.y + v.y + b4.y;
      rr.z = old.z + v.z + b4.z; rr.w = old.w + v.w + b4.w;
      *(float4*)gp = rr;
      s_acc += (rr.x + rr.y) + (rr.z + rr.w);
      q_acc += (rr.x*rr.x + rr.y*rr.y) + (rr.z*rr.z + rr.w*rr.w);
    }
#pragma unroll
    for (int off = 32; off > 0; off >>= 1) {
      s_acc += __shfl_down(s_acc, off);
      q_acc += __shfl_down(q_acc, off);
    }
    if (lane == 0) {
      atomicAdd(&stats[0], s_acc);
      atomicAdd(&stats[1], q_acc);
    }
  }
}

// =====================================================================
// V transpose: vc2[hm][tok] = qkv[tok][1024+hm]  (hm = h*64+hd head-major)
// =====================================================================
__global__ __launch_bounds__(256) void perm_v2(const f16* __restrict__ qkv,
                                               f16* __restrict__ vc) {
  __shared__ f16 t[64][72];
  int t0 = blockIdx.x * 64, c0 = blockIdx.y * 64;
  for (int id = threadIdx.x; id < 512; id += 256) {
    int row = id >> 3, cc = id & 7;
    *(f16x8*)&t[row][cc * 8] =
        *(const f16x8*)&qkv[(size_t)(t0 + row) * 1536 + 1024 + c0 + cc * 8];
  }
  __syncthreads();
  for (int id = threadIdx.x; id < 512; id += 256) {
    int row = id >> 3, cc = id & 7;
    f16x8 o;
#pragma unroll
    for (int u = 0; u < 8; ++u) o[u] = t[cc * 8 + u][row];
    *(f16x8*)&vc[(size_t)(c0 + row) * NTOK + t0 + cc * 8] = o;
  }
}

// =====================================================================
// MFMA f16 flash attention (fixed-max exp2 softmax; Q pre-scaled in weights).
// qkv [4096][1536]: q cols 0..511 / k cols 512..1023, head-major (h*64+hd).
// vc [512][4096]: row = h*64+hd. out o [4096][512]: col = h*64+hd.
// Double-buffered gload_lds K/V staging, 1 barrier/iter. sigma K-row perm
// makes each lane's 8 P values contiguous -> ds_write_b128, conflict-free.
// =====================================================================
__global__ __launch_bounds__(256) void attn2(const f16* __restrict__ qkv,
                                             const f16* __restrict__ vc,
                                             f16* __restrict__ o) {
  __shared__ __align__(16) f16 Ks[2][128 * 64];
  __shared__ __align__(16) f16 Vs[2][64 * 128];
  __shared__ __align__(16) f16 Ps[64 * 128];

  const int tid = threadIdx.x;
  const int lane = tid & 63, w = tid >> 6;
  const int l15 = lane & 15, hi = lane >> 4;
  const int h = blockIdx.y, q0 = blockIdx.x * 64;

  // Q fragments direct from global (pre-scaled by QSCALE via weights)
  const f16* qrow = qkv + (size_t)(q0 + w * 16 + l15) * 1536 + h * 64;
  f16x8 qf0 = *(const f16x8*)(qrow + hi * 8);
  f16x8 qf1 = *(const f16x8*)(qrow + 32 + hi * 8);

  float l_run[4] = {0.f, 0.f, 0.f, 0.f};
  f32x4 oacc[4];
#pragma unroll
  for (int nbh = 0; nbh < 4; ++nbh) oacc[nbh] = zero4();

  auto stageK = [&](int buf, int kb) {
#pragma unroll
    for (int j = 0; j < 4; ++j) {
      int flat = j * 256 + tid;
      int rho = flat >> 3, c = flat & 7;
      int key = kb * 128 + ((rho & 15) * 8 + (rho >> 4));   // sigma permutation
      gload16(qkv + (size_t)key * 1536 + 512 + h * 64 + ((c ^ (rho & 7)) * 8),
              &Ks[buf][(j * 256 + w * 64) * 8]);
    }
  };
  auto stageV = [&](int buf, int kb) {
#pragma unroll
    for (int j = 0; j < 4; ++j) {                 // FIXED: was j<2 (staged only half the V tile -> NaN)
      int flat = j * 256 + tid;
      int hd = flat >> 4, c = flat & 15;
      gload16(vc + (size_t)(h * 64 + hd) * NTOK + kb * 128 + ((c ^ (hd & 7)) * 8),
              &Vs[buf][(j * 256 + w * 64) * 8]);
    }
  };

  stageK(0, 0); stageV(0, 0);
  asm volatile("s_waitcnt vmcnt(0)" ::: "memory");
  __syncthreads();

  for (int kb = 0; kb < 32; ++kb) {
    int cur = kb & 1;
    if (kb < 31) { stageK(cur ^ 1, kb + 1); stageV(cur ^ 1, kb + 1); }

    // QK^T (S already in log2 units)
    const f16* Kb = &Ks[cur][0];
    f32x4 sacc[8];
#pragma unroll
    for (int nb = 0; nb < 8; ++nb) sacc[nb] = zero4();
#pragma unroll
    for (int nb = 0; nb < 8; ++nb) {
      int row = nb * 16 + l15;
      int sw = (row & 7) * 8;
      f16x8 k0f = *(const f16x8*)&Kb[row * 64 + ((hi * 8) ^ sw)];
      f16x8 k1f = *(const f16x8*)&Kb[row * 64 + ((32 + hi * 8) ^ sw)];
      sacc[nb] = __builtin_amdgcn_mfma_f32_16x16x32_f16(qf0, k0f, sacc[nb], 0, 0, 0);
      sacc[nb] = __builtin_amdgcn_mfma_f32_16x16x32_f16(qf1, k1f, sacc[nb], 0, 0, 0);
    }

    // fixed-max softmax: P = exp2(S); vectorized b128 P write (swizzled)
#pragma unroll
    for (int r = 0; r < 4; ++r) {
      int prow = w * 16 + hi * 4 + r;
      f16x8 pv;
      float ps = 0.f;
#pragma unroll
      for (int nb = 0; nb < 8; ++nb) {
        float p = exp2f(sacc[nb][r]);
        ps += p;
        pv[nb] = (f16)p;
      }
      *(f16x8*)&Ps[prow * 128 + ((l15 ^ (prow & 7)) * 8)] = pv;
#pragma unroll
      for (int off = 1; off < 16; off <<= 1) ps += __shfl_xor(ps, off);
      l_run[r] += ps;
    }

    // O += P * V
    const f16* Vb = &Vs[cur][0];
    {
      int prow = w * 16 + l15;
      int psw = (prow & 7) * 8;
#pragma unroll
      for (int ks2 = 0; ks2 < 4; ++ks2) {
        f16x8 pf = *(const f16x8*)&Ps[prow * 128 + ((ks2 * 32 + hi * 8) ^ psw)];
#pragma unroll
        for (int nbh = 0; nbh < 4; ++nbh) {
          int vrow = nbh * 16 + l15;
          f16x8 vf = *(const f16x8*)&Vb[vrow * 128 + ((ks2 * 32 + hi * 8) ^ ((vrow & 7) * 8))];
          oacc[nbh] = __builtin_amdgcn_mfma_f32_16x16x32_f16(pf, vf, oacc[nbh], 0, 0, 0);
        }
      }
    }
    asm volatile("s_waitcnt vmcnt(0)" ::: "memory");
    __syncthreads();
  }

  // normalize; bounce through Ps as swizzled 64x64 tile; vectorized store
  float inv[4];
#pragma unroll
  for (int r = 0; r < 4; ++r) inv[r] = 1.f / l_run[r];
  f16* Ot = Ps;
#pragma unroll
  for (int r = 0; r < 4; ++r) {
    int row = w * 16 + hi * 4 + r;
    int sw = (row & 7) * 8;
#pragma unroll
    for (int nbh = 0; nbh < 4; ++nbh) {
      int col = nbh * 16 + l15;
      Ot[row * 64 + (col ^ sw)] = (f16)(oacc[nbh][r] * inv[r]);
    }
  }
  __syncthreads();
#pragma unroll
  for (int j = 0; j < 2; ++j) {
    int flat = j * 256 + tid;
    int row = flat >> 3, c = flat & 7;
    f16x8 v = *(const f16x8*)&Ot[row * 64 + ((c ^ (row & 7)) * 8)];
    *(f16x8*)&o[(size_t)(q0 + row) * 512 + h * 64 + c * 8] = v;
  }
}

// =====================================================================
// host-side orchestration
// =====================================================================
extern "C" void kernel_launch(void* const* d_in, const int* in_sizes, int n_in,
                              void* d_out, int out_size, void* d_ws, size_t ws_size,
                              hipStream_t stream) {
  const float* x   = (const float*)d_in[0];
  const float* g1  = (const float*)d_in[1];
  const float* b1  = (const float*)d_in[2];
  const float* g2  = (const float*)d_in[3];
  const float* b2  = (const float*)d_in[4];
  const float* wq  = (const float*)d_in[5];
  const float* wk  = (const float*)d_in[6];
  const float* wv  = (const float*)d_in[7];
  const float* wp  = (const float*)d_in[8];
  const float* bp  = (const float*)d_in[9];
  const float* w1  = (const float*)d_in[10];
  const float* bb1 = (const float*)d_in[11];
  const float* w2  = (const float*)d_in[12];
  const float* bb2 = (const float*)d_in[13];

  char* base = (char*)d_ws;
  size_t off = 0;
  f16* wqkvF = (f16*)(base + off); off += (size_t)4 * 786432 * 2;    // 6291456
  f16* wpF   = (f16*)(base + off); off += (size_t)4 * 262144 * 2;    // 2097152
  f16* w1F   = (f16*)(base + off); off += (size_t)4 * 2097152 * 2;   // 16777216
  f16* w2F   = (f16*)(base + off); off += (size_t)4 * 2097152 * 2;   // 16777216
  float* xcur = (float*)(base + off); off += (size_t)TOT * 4;        // 8388608
  f16* xnT   = (f16*)(base + off); off += (size_t)TOT * 2;           // 4194304
  float* stats_raw = (float*)(base + off); off += 256;               // 9 slots x 2 f32
  char* U = base + off; off += 33554432;                             // union region
  f16* qkvT = (f16*)U;                      // [4096][1536]
  f16* vc2  = (f16*)(U + 12582912);         // [512][4096]
  f16* oatt = (f16*)(U + 16777216);         // [4096][512]
  f16* hT   = (f16*)U;                      // [4096][4096] (FFN phase)

  if (ws_size < off) return;   // ~84 MB needed

  hipMemsetAsync(stats_raw, 0, 18 * sizeof(float), stream);

  cvt_qkv<<<1536, 256, 0, stream>>>(wq, wk, wv, wqkvF);
  cvt_wp<<<512, 256, 0, stream>>>(wp, wpF);
  cvt_12<<<dim3(4096, 2), 256, 0, stream>>>(w1, w2, w1F, w2F);

  // x [512][4096] -> xcur [4096][512], fused GN stats slot 0
  transpose_k<true><<<dim3(64, 8), 256, 0, stream>>>(x, xcur, 512, 4096, stats_raw);

  for (int l = 0; l < 4; ++l) {
    // --- x = x + attn(GN1(x)) ---
    gn_apply2<<<1024, 256, 0, stream>>>(xcur, stats_raw + 2 * (2 * l),
                                        g1 + l * CDIM, b1 + l * CDIM, xnT);
    hgemm2<128, 128, 0><<<dim3(12, 32), 256, 0, stream>>>(
        xnT, wqkvF + (size_t)l * 786432, nullptr, qkvT, nullptr, nullptr, 1536, 512);
    perm_v2<<<dim3(64, 8), 256, 0, stream>>>(qkvT, vc2);
    attn2<<<dim3(64, 8), 256, 0, stream>>>(qkvT, vc2, oatt);
    hgemm2<64, 64, 2><<<dim3(8, 64), 256, 0, stream>>>(
        oatt, wpF + (size_t)l * 262144, bp + l * CDIM, nullptr, xcur,
        stats_raw + 2 * (2 * l + 1), 512, 512);

    // --- x = x + FFN(GN2(x)) ---
    gn_apply2<<<1024, 256, 0, stream>>>(xcur, stats_raw + 2 * (2 * l + 1),
                                        g2 + l * CDIM, b2 + l * CDIM, xnT);
    hgemm2<128, 128, 1><<<dim3(32, 32), 256, 0, stream>>>(
        xnT, w1F + (size_t)l * 2097152, bb1 + l * MLPD, hT, nullptr, nullptr, 4096, 512);
    hgemm2<64, 64, 2><<<dim3(8, 64), 256, 0, stream>>>(
        hT, w2F + (size_t)l * 2097152, bb2 + l * CDIM, nullptr, xcur,
        stats_raw + 2 * (2 * l + 2), 512, 4096);
  }

  // xcur [4096][512] -> d_out [512][4096]
  transpose_k<false><<<dim3(8, 64), 256, 0, stream>>>(xcur, (float*)d_out, 4096, 512, nullptr);
}

// Round 9
// 1293.800 us; speedup vs baseline: 1.0846x; 1.0846x over previous
//
#include <hip/hip_runtime.h>

#define CDIM   512
#define NTOK   4096
#define TOT    (CDIM*NTOK)
#define MLPD   4096
#define EPS    1e-5f
#define QSCALE 0.1803368801111204f   // 0.125 * log2(e): softmax scale + exp2 conversion, folded into wq

typedef _Float16 f16;
typedef _Float16 f16x4 __attribute__((ext_vector_type(4)));
typedef _Float16 f16x8 __attribute__((ext_vector_type(8)));
typedef float    f32x4 __attribute__((ext_vector_type(4)));

typedef __attribute__((address_space(3))) void lds_void;
typedef const __attribute__((address_space(1))) void glb_void;

__device__ __forceinline__ void gload16(const void* g, void* l) {
  __builtin_amdgcn_global_load_lds((glb_void*)g, (lds_void*)l, 16, 0, 0);
}

__device__ __forceinline__ f32x4 zero4() { f32x4 z; z[0]=0.f; z[1]=0.f; z[2]=0.f; z[3]=0.f; return z; }

// =====================================================================
// weight staging kernels (fp32 -> f16, permutations baked in)
// =====================================================================
__global__ __launch_bounds__(256) void cvt_qkv(const float* __restrict__ wq,
                                               const float* __restrict__ wk,
                                               const float* __restrict__ wv,
                                               f16* __restrict__ dst) {
  int i = blockIdx.x * 256 + threadIdx.x;       // 8-elem unit, total 393216
  int k0 = (i & 63) * 8;
  int rowglob = i >> 6;
  int l = rowglob / 1536;
  int n = rowglob - l * 1536;
  int sect = n >> 9, nn = n & 511;
  int h = nn >> 6, hd = nn & 63;
  int c = hd * 8 + h;
  const float* base = (sect == 0) ? wq : (sect == 1) ? wk : wv;
  const float* src = base + (size_t)l * 262144 + c * 512 + k0;
  float scl = (sect == 0) ? QSCALE : 1.f;
  float4 a = *(const float4*)src;
  float4 b = *(const float4*)(src + 4);
  f16x8 o;
  o[0]=(f16)(a.x*scl); o[1]=(f16)(a.y*scl); o[2]=(f16)(a.z*scl); o[3]=(f16)(a.w*scl);
  o[4]=(f16)(b.x*scl); o[5]=(f16)(b.y*scl); o[6]=(f16)(b.z*scl); o[7]=(f16)(b.w*scl);
  *(f16x8*)&dst[(size_t)l * 786432 + (size_t)n * 512 + k0] = o;
}

__global__ __launch_bounds__(256) void cvt_wp(const float* __restrict__ wp,
                                              f16* __restrict__ dst) {
  int i = blockIdx.x * 256 + threadIdx.x;       // 8-elem unit, total 131072
  int d0 = (i & 63) * 8;
  int rowglob = i >> 6;
  int l = rowglob >> 9, n = rowglob & 511;
  int h = d0 >> 6;
  const float* src = wp + (size_t)l * 262144 + (size_t)n * 512;
  f16x8 o;
#pragma unroll
  for (int u = 0; u < 8; ++u) {
    int hd = (d0 + u) & 63;
    o[u] = (f16)src[hd * 8 + h];
  }
  *(f16x8*)&dst[(size_t)l * 262144 + (size_t)n * 512 + d0] = o;
}

__global__ __launch_bounds__(256) void cvt_12(const float* __restrict__ w1,
                                              const float* __restrict__ w2,
                                              f16* __restrict__ d1,
                                              f16* __restrict__ d2) {
  int i = blockIdx.x * 256 + threadIdx.x;       // 8-elem unit
  const float* src = blockIdx.y ? w2 : w1;
  f16* dst = blockIdx.y ? d2 : d1;
  size_t e = (size_t)i * 8;
  float4 a = *(const float4*)(src + e);
  float4 b = *(const float4*)(src + e + 4);
  f16x8 o;
  o[0]=(f16)a.x; o[1]=(f16)a.y; o[2]=(f16)a.z; o[3]=(f16)a.w;
  o[4]=(f16)b.x; o[5]=(f16)b.y; o[6]=(f16)b.z; o[7]=(f16)b.w;
  *(f16x8*)&dst[e] = o;
}

// =====================================================================
// fp32 tiled transpose (+ optional GN stats accumulation)
// =====================================================================
template <bool STATS>
__global__ __launch_bounds__(256) void transpose_k(const float* __restrict__ src,
                                                   float* __restrict__ dst,
                                                   int R, int C,
                                                   float* __restrict__ stats) {
  __shared__ float t[64][65];
  int c0 = blockIdx.x * 64, r0 = blockIdx.y * 64;
  float s = 0.f, q = 0.f;
  for (int id = threadIdx.x; id < 1024; id += 256) {
    int row = id >> 4, cc = id & 15;
    float4 v = *(const float4*)&src[(size_t)(r0 + row) * C + c0 + cc * 4];
    *(float4*)&t[row][cc * 4] = v;
    if (STATS) {
      s += (v.x + v.y) + (v.z + v.w);
      q += (v.x*v.x + v.y*v.y) + (v.z*v.z + v.w*v.w);
    }
  }
  __syncthreads();
  for (int id = threadIdx.x; id < 1024; id += 256) {
    int row = id >> 4, cc = id & 15;
    float4 o;
    o.x = t[cc*4+0][row]; o.y = t[cc*4+1][row];
    o.z = t[cc*4+2][row]; o.w = t[cc*4+3][row];
    *(float4*)&dst[(size_t)(c0 + row) * R + r0 + cc * 4] = o;
  }
  if (STATS) {
#pragma unroll
    for (int off = 32; off > 0; off >>= 1) {
      s += __shfl_down(s, off);
      q += __shfl_down(q, off);
    }
    if ((threadIdx.x & 63) == 0) {
      atomicAdd(&stats[0], s);
      atomicAdd(&stats[1], q);
    }
  }
}

// =====================================================================
// GN apply: raw stats -> mu/rsigma inline; fp32 token-major -> f16
// =====================================================================
__global__ __launch_bounds__(256) void gn_apply2(const float* __restrict__ x,
                                                 const float* __restrict__ stats,
                                                 const float* __restrict__ g,
                                                 const float* __restrict__ b,
                                                 f16* __restrict__ out) {
  int i = blockIdx.x * 256 + threadIdx.x;       // 8-elem unit
  float mu = stats[0] * (1.f / TOT);
  float var = stats[1] * (1.f / TOT) - mu * mu;
  float rs = rsqrtf(var + EPS);
  int c0 = (i & 63) * 8;
  const float4* x4 = (const float4*)x;
  float4 a = x4[i * 2], c = x4[i * 2 + 1];
  float4 G0 = *(const float4*)(g + c0);
  float4 G1 = *(const float4*)(g + c0 + 4);
  float4 B0 = *(const float4*)(b + c0);
  float4 B1 = *(const float4*)(b + c0 + 4);
  f16x8 o;
  o[0]=(f16)((a.x-mu)*rs*G0.x+B0.x); o[1]=(f16)((a.y-mu)*rs*G0.y+B0.y);
  o[2]=(f16)((a.z-mu)*rs*G0.z+B0.z); o[3]=(f16)((a.w-mu)*rs*G0.w+B0.w);
  o[4]=(f16)((c.x-mu)*rs*G1.x+B1.x); o[5]=(f16)((c.y-mu)*rs*G1.y+B1.y);
  o[6]=(f16)((c.z-mu)*rs*G1.z+B1.z); o[7]=(f16)((c.w-mu)*rs*G1.w+B1.w);
  *(f16x8*)&out[(size_t)i * 8] = o;
}

// =====================================================================
// MFMA f16 GEMM, gload_lds staging, pre-swizzled global source.
// C[m][n] = sum_k A[m][k] * Bw[n][k].
// MODE 0: f16 store (LDS-bounced); 1: +bias+relu f16 store;
// MODE 2: direct fp32 RMW C += acc+bias, stats fused in registers.
// =====================================================================
template <int BM, int BN, int MODE>
__global__ __launch_bounds__(256) void hgemm2(const f16* __restrict__ A,
                                              const f16* __restrict__ Bw,
                                              const float* __restrict__ bias,
                                              f16* __restrict__ Cf16,
                                              float* __restrict__ Cf32,
                                              float* __restrict__ stats,
                                              int N, int K) {
  constexpr int MB = BM / 32, NB = BN / 32;     // fragments per wave (2x2 wave grid)
  __shared__ __align__(16) f16 SM[(BM + BN) * 64];
  f16* As = SM;
  f16* Bs = SM + BM * 64;

  const int tid = threadIdx.x;
  const int lane = tid & 63, wid = tid >> 6;
  const int wm = wid >> 1, wn = wid & 1;
  const int m0 = blockIdx.y * BM, n0 = blockIdx.x * BN;
  const int l15 = lane & 15, hi = lane >> 4;

  f32x4 acc[MB][NB];
#pragma unroll
  for (int mb = 0; mb < MB; ++mb)
#pragma unroll
    for (int nb = 0; nb < NB; ++nb) acc[mb][nb] = zero4();

  for (int k0 = 0; k0 < K; k0 += 64) {
#pragma unroll
    for (int j = 0; j < BM / 32; ++j) {
      int flat = j * 256 + tid;
      int row = flat >> 3, c = flat & 7;
      gload16(&A[(size_t)(m0 + row) * K + k0 + ((c ^ (row & 7)) * 8)],
              &As[(j * 256 + wid * 64) * 8]);
    }
#pragma unroll
    for (int j = 0; j < BN / 32; ++j) {
      int flat = j * 256 + tid;
      int row = flat >> 3, c = flat & 7;
      gload16(&Bw[(size_t)(n0 + row) * K + k0 + ((c ^ (row & 7)) * 8)],
              &Bs[(j * 256 + wid * 64) * 8]);
    }
    asm volatile("s_waitcnt vmcnt(0)" ::: "memory");
    __syncthreads();
#pragma unroll
    for (int ks = 0; ks < 2; ++ks) {
      f16x8 af[MB], bf[NB];
#pragma unroll
      for (int mb = 0; mb < MB; ++mb) {
        int row = wm * (BM / 2) + mb * 16 + l15;
        af[mb] = *(const f16x8*)&As[row * 64 + ((ks * 32 + hi * 8) ^ ((row & 7) * 8))];
      }
#pragma unroll
      for (int nb = 0; nb < NB; ++nb) {
        int row = wn * (BN / 2) + nb * 16 + l15;
        bf[nb] = *(const f16x8*)&Bs[row * 64 + ((ks * 32 + hi * 8) ^ ((row & 7) * 8))];
      }
#pragma unroll
      for (int mb = 0; mb < MB; ++mb)
#pragma unroll
        for (int nb = 0; nb < NB; ++nb)
          acc[mb][nb] = __builtin_amdgcn_mfma_f32_16x16x32_f16(af[mb], bf[nb], acc[mb][nb], 0, 0, 0);
    }
    __syncthreads();
  }

  if constexpr (MODE <= 1) {
    // LDS-bounced f16 epilogue (swizzled tile, vectorized global store)
    f16* Co = SM;                               // BM*BN f16 <= (BM+BN)*64
#pragma unroll
    for (int mb = 0; mb < MB; ++mb)
#pragma unroll
      for (int nb = 0; nb < NB; ++nb) {
        int colb = wn * (BN / 2) + nb * 16 + l15;
        float bv = 0.f;
        if constexpr (MODE == 1) bv = bias[n0 + colb];
#pragma unroll
        for (int r = 0; r < 4; ++r) {
          int row = wm * (BM / 2) + mb * 16 + hi * 4 + r;
          float v = acc[mb][nb][r];
          if constexpr (MODE == 1) v = fmaxf(v + bv, 0.f);
          Co[row * BN + (colb ^ ((row & 7) * 8))] = (f16)v;
        }
      }
    __syncthreads();
#pragma unroll
    for (int j = 0; j < BM * BN / 2048; ++j) {
      int flat = j * 256 + tid;
      int row = flat / (BN / 8), c = flat % (BN / 8);
      f16x8 v = *(const f16x8*)&Co[row * BN + ((c * 8) ^ ((row & 7) * 8))];
      *(f16x8*)&Cf16[(size_t)(m0 + row) * N + n0 + c * 8] = v;
    }
  } else {
    // MODE 2: direct fp32 RMW (+bias); GN stats accumulated in registers
    float s_acc = 0.f, q_acc = 0.f;
    const int rbase = m0 + wm * (BM / 2) + hi * 4;
#pragma unroll
    for (int mb = 0; mb < MB; ++mb) {
#pragma unroll
      for (int nb = 0; nb < NB; ++nb) {
        int col = n0 + wn * (BN / 2) + nb * 16 + l15;
        float bv = bias[col];
#pragma unroll
        for (int r = 0; r < 4; ++r) {
          int row = rbase + mb * 16 + r;
          float* gp = &Cf32[(size_t)row * N + col];
          float rr = *gp + acc[mb][nb][r] + bv;
          *gp = rr;
          s_acc += rr;
          q_acc += rr * rr;
        }
      }
    }
#pragma unroll
    for (int off = 32; off > 0; off >>= 1) {
      s_acc += __shfl_down(s_acc, off);
      q_acc += __shfl_down(q_acc, off);
    }
    if (lane == 0) {
      atomicAdd(&stats[0], s_acc);
      atomicAdd(&stats[1], q_acc);
    }
  }
}

// =====================================================================
// V transpose: vc2[hm][tok] = qkv[tok][1024+hm]  (hm = h*64+hd head-major)
// =====================================================================
__global__ __launch_bounds__(256) void perm_v2(const f16* __restrict__ qkv,
                                               f16* __restrict__ vc) {
  __shared__ f16 t[64][72];
  int t0 = blockIdx.x * 64, c0 = blockIdx.y * 64;
  for (int id = threadIdx.x; id < 512; id += 256) {
    int row = id >> 3, cc = id & 7;
    *(f16x8*)&t[row][cc * 8] =
        *(const f16x8*)&qkv[(size_t)(t0 + row) * 1536 + 1024 + c0 + cc * 8];
  }
  __syncthreads();
  for (int id = threadIdx.x; id < 512; id += 256) {
    int row = id >> 3, cc = id & 7;
    f16x8 o;
#pragma unroll
    for (int u = 0; u < 8; ++u) o[u] = t[cc * 8 + u][row];
    *(f16x8*)&vc[(size_t)(c0 + row) * NTOK + t0 + cc * 8] = o;
  }
}

// =====================================================================
// MFMA f16 flash attention, KVBLK=64 (LDS 40KB -> 4 blocks/CU).
// qkv [4096][1536] head-major q/k; vc [512][4096]; out o [4096][512].
// sigma K-row perm: LDS row rho holds key (rho&15)*4+(rho>>4) so each
// lane's 4 P values are contiguous -> ds_write_b64, conflict-free.
// =====================================================================
__global__ __launch_bounds__(256) void attn2(const f16* __restrict__ qkv,
                                             const f16* __restrict__ vc,
                                             f16* __restrict__ o) {
  __shared__ __align__(16) f16 Ks[2][64 * 64];   // 16 KB
  __shared__ __align__(16) f16 Vs[2][64 * 64];   // 16 KB
  __shared__ __align__(16) f16 Ps[64 * 64];      // 8 KB

  const int tid = threadIdx.x;
  const int lane = tid & 63, w = tid >> 6;
  const int l15 = lane & 15, hi = lane >> 4;
  const int h = blockIdx.y, q0 = blockIdx.x * 64;

  const f16* qrow = qkv + (size_t)(q0 + w * 16 + l15) * 1536 + h * 64;
  f16x8 qf0 = *(const f16x8*)(qrow + hi * 8);
  f16x8 qf1 = *(const f16x8*)(qrow + 32 + hi * 8);

  float l_run[4] = {0.f, 0.f, 0.f, 0.f};
  f32x4 oacc[4];
#pragma unroll
  for (int nbh = 0; nbh < 4; ++nbh) oacc[nbh] = zero4();

  auto stageK = [&](int buf, int kb) {
#pragma unroll
    for (int j = 0; j < 2; ++j) {
      int flat = j * 256 + tid;
      int rho = flat >> 3, c = flat & 7;
      int key = kb * 64 + ((rho & 15) * 4 + (rho >> 4));   // sigma
      gload16(qkv + (size_t)key * 1536 + 512 + h * 64 + ((c ^ (rho & 7)) * 8),
              &Ks[buf][(j * 256 + w * 64) * 8]);
    }
  };
  auto stageV = [&](int buf, int kb) {
#pragma unroll
    for (int j = 0; j < 2; ++j) {
      int flat = j * 256 + tid;
      int hd = flat >> 3, c = flat & 7;
      gload16(vc + (size_t)(h * 64 + hd) * NTOK + kb * 64 + ((c ^ (hd & 7)) * 8),
              &Vs[buf][(j * 256 + w * 64) * 8]);
    }
  };

  stageK(0, 0); stageV(0, 0);
  asm volatile("s_waitcnt vmcnt(0)" ::: "memory");
  __syncthreads();

  for (int kb = 0; kb < 64; ++kb) {
    int cur = kb & 1;
    if (kb < 63) { stageK(cur ^ 1, kb + 1); stageV(cur ^ 1, kb + 1); }

    // QK^T (S in log2 units; Q pre-scaled via weights)
    const f16* Kb = &Ks[cur][0];
    f32x4 sacc[4];
#pragma unroll
    for (int nb = 0; nb < 4; ++nb) sacc[nb] = zero4();
    __builtin_amdgcn_s_setprio(1);
#pragma unroll
    for (int nb = 0; nb < 4; ++nb) {
      int row = nb * 16 + l15;
      int sw = (row & 7) * 8;
      f16x8 k0f = *(const f16x8*)&Kb[row * 64 + ((hi * 8) ^ sw)];
      f16x8 k1f = *(const f16x8*)&Kb[row * 64 + ((32 + hi * 8) ^ sw)];
      sacc[nb] = __builtin_amdgcn_mfma_f32_16x16x32_f16(qf0, k0f, sacc[nb], 0, 0, 0);
      sacc[nb] = __builtin_amdgcn_mfma_f32_16x16x32_f16(qf1, k1f, sacc[nb], 0, 0, 0);
    }
    __builtin_amdgcn_s_setprio(0);

    // fixed-max softmax: P = exp2(S); contiguous b64 P write (swizzled)
#pragma unroll
    for (int r = 0; r < 4; ++r) {
      int prow = w * 16 + hi * 4 + r;
      f16x4 pv;
      float ps = 0.f;
#pragma unroll
      for (int nb = 0; nb < 4; ++nb) {
        float p = exp2f(sacc[nb][r]);
        ps += p;
        pv[nb] = (f16)p;                         // key = l15*4 + nb (contiguous)
      }
      *(f16x4*)&Ps[prow * 64 + ((l15 * 4) ^ ((prow & 7) * 8))] = pv;
#pragma unroll
      for (int off = 1; off < 16; off <<= 1) ps += __shfl_xor(ps, off);
      l_run[r] += ps;
    }

    // O += P * V
    const f16* Vb = &Vs[cur][0];
    {
      int prow = w * 16 + l15;
      int psw = (prow & 7) * 8;
      __builtin_amdgcn_s_setprio(1);
#pragma unroll
      for (int ks2 = 0; ks2 < 2; ++ks2) {
        f16x8 pf = *(const f16x8*)&Ps[prow * 64 + ((ks2 * 32 + hi * 8) ^ psw)];
#pragma unroll
        for (int nbh = 0; nbh < 4; ++nbh) {
          int vrow = nbh * 16 + l15;
          f16x8 vf = *(const f16x8*)&Vb[vrow * 64 + ((ks2 * 32 + hi * 8) ^ ((vrow & 7) * 8))];
          oacc[nbh] = __builtin_amdgcn_mfma_f32_16x16x32_f16(pf, vf, oacc[nbh], 0, 0, 0);
        }
      }
      __builtin_amdgcn_s_setprio(0);
    }
    asm volatile("s_waitcnt vmcnt(0)" ::: "memory");
    __syncthreads();
  }

  // normalize; bounce through Ps as swizzled 64x64 tile; vectorized store
  float inv[4];
#pragma unroll
  for (int r = 0; r < 4; ++r) inv[r] = 1.f / l_run[r];
  f16* Ot = Ps;
#pragma unroll
  for (int r = 0; r < 4; ++r) {
    int row = w * 16 + hi * 4 + r;
    int sw = (row & 7) * 8;
#pragma unroll
    for (int nbh = 0; nbh < 4; ++nbh) {
      int col = nbh * 16 + l15;
      Ot[row * 64 + (col ^ sw)] = (f16)(oacc[nbh][r] * inv[r]);
    }
  }
  __syncthreads();
#pragma unroll
  for (int j = 0; j < 2; ++j) {
    int flat = j * 256 + tid;
    int row = flat >> 3, c = flat & 7;
    f16x8 v = *(const f16x8*)&Ot[row * 64 + ((c ^ (row & 7)) * 8)];
    *(f16x8*)&o[(size_t)(q0 + row) * 512 + h * 64 + c * 8] = v;
  }
}

// =====================================================================
// host-side orchestration
// =====================================================================
extern "C" void kernel_launch(void* const* d_in, const int* in_sizes, int n_in,
                              void* d_out, int out_size, void* d_ws, size_t ws_size,
                              hipStream_t stream) {
  const float* x   = (const float*)d_in[0];
  const float* g1  = (const float*)d_in[1];
  const float* b1  = (const float*)d_in[2];
  const float* g2  = (const float*)d_in[3];
  const float* b2  = (const float*)d_in[4];
  const float* wq  = (const float*)d_in[5];
  const float* wk  = (const float*)d_in[6];
  const float* wv  = (const float*)d_in[7];
  const float* wp  = (const float*)d_in[8];
  const float* bp  = (const float*)d_in[9];
  const float* w1  = (const float*)d_in[10];
  const float* bb1 = (const float*)d_in[11];
  const float* w2  = (const float*)d_in[12];
  const float* bb2 = (const float*)d_in[13];

  char* base = (char*)d_ws;
  size_t off = 0;
  f16* wqkvF = (f16*)(base + off); off += (size_t)4 * 786432 * 2;
  f16* wpF   = (f16*)(base + off); off += (size_t)4 * 262144 * 2;
  f16* w1F   = (f16*)(base + off); off += (size_t)4 * 2097152 * 2;
  f16* w2F   = (f16*)(base + off); off += (size_t)4 * 2097152 * 2;
  float* xcur = (float*)(base + off); off += (size_t)TOT * 4;
  f16* xnT   = (f16*)(base + off); off += (size_t)TOT * 2;
  float* stats_raw = (float*)(base + off); off += 256;
  char* U = base + off; off += 33554432;
  f16* qkvT = (f16*)U;                      // [4096][1536]
  f16* vc2  = (f16*)(U + 12582912);         // [512][4096]
  f16* oatt = (f16*)(U + 16777216);         // [4096][512]
  f16* hT   = (f16*)U;                      // [4096][4096] (FFN phase)

  if (ws_size < off) return;

  hipMemsetAsync(stats_raw, 0, 18 * sizeof(float), stream);

  cvt_qkv<<<1536, 256, 0, stream>>>(wq, wk, wv, wqkvF);
  cvt_wp<<<512, 256, 0, stream>>>(wp, wpF);
  cvt_12<<<dim3(4096, 2), 256, 0, stream>>>(w1, w2, w1F, w2F);

  transpose_k<true><<<dim3(64, 8), 256, 0, stream>>>(x, xcur, 512, 4096, stats_raw);

  for (int l = 0; l < 4; ++l) {
    // --- x = x + attn(GN1(x)) ---
    gn_apply2<<<1024, 256, 0, stream>>>(xcur, stats_raw + 2 * (2 * l),
                                        g1 + l * CDIM, b1 + l * CDIM, xnT);
    hgemm2<128, 128, 0><<<dim3(12, 32), 256, 0, stream>>>(
        xnT, wqkvF + (size_t)l * 786432, nullptr, qkvT, nullptr, nullptr, 1536, 512);
    perm_v2<<<dim3(64, 8), 256, 0, stream>>>(qkvT, vc2);
    attn2<<<dim3(64, 8), 256, 0, stream>>>(qkvT, vc2, oatt);
    hgemm2<64, 128, 2><<<dim3(4, 64), 256, 0, stream>>>(
        oatt, wpF + (size_t)l * 262144, bp + l * CDIM, nullptr, xcur,
        stats_raw + 2 * (2 * l + 1), 512, 512);

    // --- x = x + FFN(GN2(x)) ---
    gn_apply2<<<1024, 256, 0, stream>>>(xcur, stats_raw + 2 * (2 * l + 1),
                                        g2 + l * CDIM, b2 + l * CDIM, xnT);
    hgemm2<128, 128, 1><<<dim3(32, 32), 256, 0, stream>>>(
        xnT, w1F + (size_t)l * 2097152, bb1 + l * MLPD, hT, nullptr, nullptr, 4096, 512);
    hgemm2<64, 128, 2><<<dim3(4, 64), 256, 0, stream>>>(
        hT, w2F + (size_t)l * 2097152, bb2 + l * CDIM, nullptr, xcur,
        stats_raw + 2 * (2 * l + 2), 512, 4096);
  }

  transpose_k<false><<<dim3(8, 64), 256, 0, stream>>>(xcur, (float*)d_out, 4096, 512, nullptr);
}